// Round 14
// baseline (451.127 us; speedup 1.0000x reference)
//
#include <hip/hip_runtime.h>
#include <hip/hip_bf16.h>

#define HD 128
#define HIDD 256
#define EPS_MSG 1e-7f
#define EPS_SM 1e-16f
#define LN_EPS 1e-5f
#define HP2 264     // s_hm row stride (bf16 elems)
#define LOG2E 1.44269504f

typedef __attribute__((ext_vector_type(8))) short bf16x8;
typedef __attribute__((ext_vector_type(4))) float f32x4;
typedef __attribute__((ext_vector_type(4))) ushort u16x4;

static __device__ __forceinline__ float wave_reduce_sum(float v) {
#pragma unroll
    for (int off = 32; off >= 1; off >>= 1) v += __shfl_xor(v, off, 64);
    return v;
}

static __device__ __forceinline__ float u2f(unsigned v) {
    union { float f; unsigned u; } x;
    x.u = v;
    return x.f;
}
static __device__ __forceinline__ ushort f2bf(float f) {
    __hip_bfloat16 b = __float2bfloat16(f);
    return *(ushort*)&b;
}
static __device__ __forceinline__ unsigned packbf(float lo, float hi) {
    return (unsigned)f2bf(lo) | ((unsigned)f2bf(hi) << 16);
}

// ---------------- fused encoder + layer-0 LN+ReLU ----------------
__global__ __launch_bounds__(256) void enc_ln_kernel(const float* __restrict__ x,
                                                     const float* __restrict__ W,
                                                     const float* __restrict__ b,
                                                     const float* __restrict__ g,
                                                     const float* __restrict__ bt,
                                                     unsigned* __restrict__ hp,
                                                     unsigned* __restrict__ zp, int N) {
    int node = blockIdx.x * 4 + (threadIdx.x >> 6);
    int lane = threadIdx.x & 63;
    if (node >= N) return;
    float xr[7];
#pragma unroll
    for (int j = 0; j < 7; ++j) xr[j] = x[node * 7 + j];
    float v0 = b[lane], v1 = b[lane + 64];
#pragma unroll
    for (int j = 0; j < 7; ++j) {
        v0 = fmaf(xr[j], W[j * HD + lane], v0);
        v1 = fmaf(xr[j], W[j * HD + lane + 64], v1);
    }
    float s = wave_reduce_sum(v0 + v1);
    float ss = wave_reduce_sum(v0 * v0 + v1 * v1);
    float mu = s * (1.f / 128.f);
    float var = ss * (1.f / 128.f) - mu * mu;
    float rstd = rsqrtf(var + LN_EPS);
    float z0 = fmaxf((v0 - mu) * rstd * g[lane] + bt[lane], 0.f);
    float z1 = fmaxf((v1 - mu) * rstd * g[lane + 64] + bt[lane + 64], 0.f);
    int i0 = (2 * lane) & 63, i1 = (2 * lane + 1) & 63;
    float he_lo = __shfl(v0, i0), ho_lo = __shfl(v0, i1);
    float he_hi = __shfl(v1, i0), ho_hi = __shfl(v1, i1);
    float hce = (lane < 32) ? he_lo : he_hi;
    float hco = (lane < 32) ? ho_lo : ho_hi;
    hp[(size_t)node * 64 + lane] = packbf(hce, hco);
    float e_lo = __shfl(z0, i0), o_lo = __shfl(z0, i1);
    float e_hi = __shfl(z1, i0), o_hi = __shfl(z1, i1);
    float ce = (lane < 32) ? e_lo : e_hi;
    float co = (lane < 32) ? o_lo : o_hi;
    zp[(size_t)node * 64 + lane] = packbf(ce, co);
}

// ---------------- weight convert + transpose to bf16 ----------------
__global__ __launch_bounds__(256) void wconv_kernel(const float* __restrict__ W1,
                                                    const float* __restrict__ W2,
                                                    ushort* __restrict__ W1t,
                                                    ushort* __restrict__ W2t, int L) {
    int gid = blockIdx.x * 256 + threadIdx.x;
    int per = HD * HIDD;  // 32768
    int tot = L * per;
    if (gid < tot) {
        int l = gid / per, r = gid % per;
        int n = r >> 7, k = r & 127;
        W1t[gid] = f2bf(W1[(size_t)l * per + (size_t)k * HIDD + n]);
    } else if (gid < 2 * tot) {
        int g2 = gid - tot;
        int l = g2 / per, r = g2 % per;
        int n = r >> 8, k = r & 255;
        W2t[g2] = f2bf(W2[(size_t)l * per + (size_t)k * HD + n]);
    }
}

// ---------------- CSR build ----------------
__global__ __launch_bounds__(256) void count_kernel(const int* __restrict__ dst, int* __restrict__ cnt, int E) {
    int e = blockIdx.x * 256 + threadIdx.x;
    if (e < E) atomicAdd(&cnt[dst[e]], 1);
}

__global__ __launch_bounds__(256) void scanA_kernel(const int* __restrict__ cnt, int* __restrict__ row_ptr,
                                                    int* __restrict__ blk_sums, int n) {
    __shared__ int sb[256];
    int tid = threadIdx.x;
    int idx = blockIdx.x * 256 + tid;
    int v = (idx < n) ? cnt[idx] : 0;
    sb[tid] = v;
    __syncthreads();
#pragma unroll
    for (int off = 1; off < 256; off <<= 1) {
        int x = (tid >= off) ? sb[tid - off] : 0;
        __syncthreads();
        sb[tid] += x;
        __syncthreads();
    }
    if (idx < n) row_ptr[idx + 1] = sb[tid];
    if (tid == 255) blk_sums[blockIdx.x] = sb[255];
}

__global__ __launch_bounds__(256) void scanB_kernel(int* __restrict__ blk_sums, int nblk) {
    __shared__ int sb[256];
    int tid = threadIdx.x;
    int v = (tid < nblk) ? blk_sums[tid] : 0;
    sb[tid] = v;
    __syncthreads();
#pragma unroll
    for (int off = 1; off < 256; off <<= 1) {
        int x = (tid >= off) ? sb[tid - off] : 0;
        __syncthreads();
        sb[tid] += x;
        __syncthreads();
    }
    if (tid < nblk) blk_sums[tid] = sb[tid];
}

__global__ __launch_bounds__(256) void scanC_kernel(int* __restrict__ row_ptr, const int* __restrict__ blk_sums,
                                                    int* __restrict__ cursor, int n) {
    int idx = blockIdx.x * 256 + threadIdx.x;
    if (idx == 0) { row_ptr[0] = 0; cursor[0] = 0; }
    if (idx < n) {
        int b = idx >> 8;
        int v = row_ptr[idx + 1] + ((b > 0) ? blk_sums[b - 1] : 0);
        row_ptr[idx + 1] = v;
        if (idx + 1 < n) cursor[idx + 1] = v;
    }
}

__global__ __launch_bounds__(256) void scatter_kernel(const int* __restrict__ src, const int* __restrict__ dst,
                                                      int* __restrict__ cursor, int* __restrict__ esrc, int E) {
    int e = blockIdx.x * 256 + threadIdx.x;
    if (e < E) {
        int v = dst[e];
        int pos = atomicAdd(&cursor[v], 1);
        esrc[pos] = src[e];
    }
}

// ---------------- aggregation: triple-node per wave, 12 gathers in flight ----------------
// Each wave processes THREE nodes' edge lists jointly (independent chains). Constant-shift
// softmax (z post-LN => logits <= ~12*tv). Per-node 4-deep tails handle degree mismatch.
__global__ __launch_bounds__(256) void agg_kernel(const unsigned* __restrict__ zp,
                                                  const int* __restrict__ row_ptr,
                                                  const int* __restrict__ esrc,
                                                  const float* __restrict__ t_all, int layer,
                                                  unsigned* __restrict__ obuf, int N) {
    int wid = threadIdx.x >> 6;
    int lane = threadIdx.x & 63;
    int n0 = __builtin_amdgcn_readfirstlane(blockIdx.x * 12 + wid * 3);
    if (n0 >= N) return;
    bool has1 = (n0 + 1) < N;
    bool has2 = (n0 + 2) < N;

    const float tv = t_all[layer];
    const float M = 12.f * fmaxf(tv, 1.f);
    const float tv2 = tv * LOG2E;
    const float mM2 = -M * LOG2E;

    int begA = row_ptr[n0], endA = row_ptr[n0 + 1];
    int begB = has1 ? row_ptr[n0 + 1] : 0;
    int endB = has1 ? row_ptr[n0 + 2] : 0;
    int begC = has2 ? row_ptr[n0 + 2] : 0;
    int endC = has2 ? row_ptr[n0 + 3] : 0;

    unsigned psA = zp[(size_t)n0 * 64 + lane];
    unsigned psB = has1 ? zp[(size_t)(n0 + 1) * 64 + lane] : 0u;
    unsigned psC = has2 ? zp[(size_t)(n0 + 2) * 64 + lane] : 0u;

    float seA0 = 0.f, seA1 = 0.f, swA0 = 0.f, swA1 = 0.f;
    float teA0 = 0.f, teA1 = 0.f, twA0 = 0.f, twA1 = 0.f;
    float seB0 = 0.f, seB1 = 0.f, swB0 = 0.f, swB1 = 0.f;
    float teB0 = 0.f, teB1 = 0.f, twB0 = 0.f, twB1 = 0.f;
    float seC0 = 0.f, seC1 = 0.f, swC0 = 0.f, swC1 = 0.f;
    float teC0 = 0.f, teC1 = 0.f, twC0 = 0.f, twC1 = 0.f;

#define AGG_EDGE(P, E0, E1, W0, W1)                                   \
    {                                                                  \
        float a0 = u2f((P) << 16) + EPS_MSG;                           \
        float a1 = u2f((P) & 0xffff0000u) + EPS_MSG;                   \
        float x0 = __builtin_amdgcn_exp2f(fmaf(a0, tv2, mM2));         \
        float x1 = __builtin_amdgcn_exp2f(fmaf(a1, tv2, mM2));         \
        E0 += x0;                                                      \
        E1 += x1;                                                      \
        W0 = fmaf(x0, a0, W0);                                         \
        W1 = fmaf(x1, a1, W1);                                         \
    }

#define GATHER4(EIDX, P0, P1, P2, P3)                                  \
    {                                                                  \
        int i0 = esrc[EIDX], i1 = esrc[(EIDX) + 1];                    \
        int i2 = esrc[(EIDX) + 2], i3 = esrc[(EIDX) + 3];              \
        P0 = zp[(size_t)i0 * 64 + lane];                               \
        P1 = zp[(size_t)i1 * 64 + lane];                               \
        P2 = zp[(size_t)i2 * 64 + lane];                               \
        P3 = zp[(size_t)i3 * 64 + lane];                               \
    }

    int eA = begA, eB = begB, eC = begC;

    // ---- joint main loop: 4 edges from each of A,B,C (12 gathers in flight) ----
    while (eA + 4 <= endA && eB + 4 <= endB && eC + 4 <= endC) {
        unsigned pA0, pA1, pA2, pA3, pB0, pB1, pB2, pB3, pC0, pC1, pC2, pC3;
        GATHER4(eA, pA0, pA1, pA2, pA3)
        GATHER4(eB, pB0, pB1, pB2, pB3)
        GATHER4(eC, pC0, pC1, pC2, pC3)
        AGG_EDGE(pA0, seA0, seA1, swA0, swA1)
        AGG_EDGE(pA1, seA0, seA1, swA0, swA1)
        AGG_EDGE(pA2, teA0, teA1, twA0, twA1)
        AGG_EDGE(pA3, teA0, teA1, twA0, twA1)
        AGG_EDGE(pB0, seB0, seB1, swB0, swB1)
        AGG_EDGE(pB1, seB0, seB1, swB0, swB1)
        AGG_EDGE(pB2, teB0, teB1, twB0, twB1)
        AGG_EDGE(pB3, teB0, teB1, twB0, twB1)
        AGG_EDGE(pC0, seC0, seC1, swC0, swC1)
        AGG_EDGE(pC1, seC0, seC1, swC0, swC1)
        AGG_EDGE(pC2, teC0, teC1, twC0, twC1)
        AGG_EDGE(pC3, teC0, teC1, twC0, twC1)
        eA += 4;
        eB += 4;
        eC += 4;
    }
    // ---- tail A ----
    while (eA + 4 <= endA) {
        unsigned p0, p1, p2, p3;
        GATHER4(eA, p0, p1, p2, p3)
        AGG_EDGE(p0, seA0, seA1, swA0, swA1)
        AGG_EDGE(p1, seA0, seA1, swA0, swA1)
        AGG_EDGE(p2, teA0, teA1, twA0, twA1)
        AGG_EDGE(p3, teA0, teA1, twA0, twA1)
        eA += 4;
    }
    for (; eA < endA; ++eA) {
        unsigned p0 = zp[(size_t)esrc[eA] * 64 + lane];
        AGG_EDGE(p0, seA0, seA1, swA0, swA1)
    }
    // ---- tail B ----
    while (eB + 4 <= endB) {
        unsigned p0, p1, p2, p3;
        GATHER4(eB, p0, p1, p2, p3)
        AGG_EDGE(p0, seB0, seB1, swB0, swB1)
        AGG_EDGE(p1, seB0, seB1, swB0, swB1)
        AGG_EDGE(p2, teB0, teB1, twB0, twB1)
        AGG_EDGE(p3, teB0, teB1, twB0, twB1)
        eB += 4;
    }
    for (; eB < endB; ++eB) {
        unsigned p0 = zp[(size_t)esrc[eB] * 64 + lane];
        AGG_EDGE(p0, seB0, seB1, swB0, swB1)
    }
    // ---- tail C ----
    while (eC + 4 <= endC) {
        unsigned p0, p1, p2, p3;
        GATHER4(eC, p0, p1, p2, p3)
        AGG_EDGE(p0, seC0, seC1, swC0, swC1)
        AGG_EDGE(p1, seC0, seC1, swC0, swC1)
        AGG_EDGE(p2, teC0, teC1, twC0, twC1)
        AGG_EDGE(p3, teC0, teC1, twC0, twC1)
        eC += 4;
    }
    for (; eC < endC; ++eC) {
        unsigned p0 = zp[(size_t)esrc[eC] * 64 + lane];
        AGG_EDGE(p0, seC0, seC1, swC0, swC1)
    }
#undef GATHER4
#undef AGG_EDGE

    // ---- finalize ----
    {
        float se0 = seA0 + teA0, se1 = seA1 + teA1;
        float sw0 = swA0 + twA0, sw1 = swA1 + twA1;
        float a0 = (endA > begA) ? sw0 / (se0 + EPS_SM) : 0.f;
        float a1 = (endA > begA) ? sw1 / (se1 + EPS_SM) : 0.f;
        float z0 = u2f(psA << 16), z1 = u2f(psA & 0xffff0000u);
        obuf[(size_t)n0 * 64 + lane] = packbf(a0 + z0, a1 + z1);
    }
    if (has1) {
        float se0 = seB0 + teB0, se1 = seB1 + teB1;
        float sw0 = swB0 + twB0, sw1 = swB1 + twB1;
        float a0 = (endB > begB) ? sw0 / (se0 + EPS_SM) : 0.f;
        float a1 = (endB > begB) ? sw1 / (se1 + EPS_SM) : 0.f;
        float z0 = u2f(psB << 16), z1 = u2f(psB & 0xffff0000u);
        obuf[(size_t)(n0 + 1) * 64 + lane] = packbf(a0 + z0, a1 + z1);
    }
    if (has2) {
        float se0 = seC0 + teC0, se1 = seC1 + teC1;
        float sw0 = swC0 + twC0, sw1 = swC1 + twC1;
        float a0 = (endC > begC) ? sw0 / (se0 + EPS_SM) : 0.f;
        float a1 = (endC > begC) ? sw1 / (se1 + EPS_SM) : 0.f;
        float z0 = u2f(psC << 16), z1 = u2f(psC & 0xffff0000u);
        obuf[(size_t)(n0 + 2) * 64 + lane] = packbf(a0 + z0, a1 + z1);
    }
}

// ---------------- persistent MFMA MLP (R8 structure): hp += relu(LN(obuf@W1+b1))@W2 + b2 ----------------
__global__ __launch_bounds__(256) void mlp_kernel(const ushort* __restrict__ obuf,
                                                  unsigned* __restrict__ hp,
                                                  const ushort* __restrict__ W1t, const float* __restrict__ b1,
                                                  const float* __restrict__ g1, const float* __restrict__ bb1,
                                                  const ushort* __restrict__ W2t, const float* __restrict__ b2,
                                                  const float* __restrict__ gnext, const float* __restrict__ btnext,
                                                  unsigned* __restrict__ zp, int fuse,
                                                  int ntiles, int N) {
    __shared__ ushort s_hm[32 * HP2];   // 16896 B
    __shared__ float s_part[32 * 8];    // 1024 B

    int tid = threadIdx.x;
    int wid = tid >> 6, lane = tid & 63;
    int l15 = lane & 15, q = lane >> 4;

    // ---- hoist ALL weight fragments (tile-invariant) ----
    bf16x8 w1f[4][4];
#pragma unroll
    for (int kk = 0; kk < 4; ++kk)
#pragma unroll
        for (int nb = 0; nb < 4; ++nb)
            w1f[kk][nb] = *(const bf16x8*)&W1t[(size_t)(wid * 64 + nb * 16 + l15) * HD + kk * 32 + q * 8];
    bf16x8 w2f[8][2];
#pragma unroll
    for (int kk = 0; kk < 8; ++kk)
#pragma unroll
        for (int nb = 0; nb < 2; ++nb)
            w2f[kk][nb] = *(const bf16x8*)&W2t[(size_t)(wid * 32 + nb * 16 + l15) * HIDD + kk * 32 + q * 8];

    for (int tile = blockIdx.x; tile < ntiles; tile += gridDim.x) {
        int row0 = tile * 32;

        // ---- per-tile input loads ----
        uint2 hpre[2][2];
        bf16x8 bfr[4][2];
#pragma unroll
        for (int mb = 0; mb < 2; ++mb) {
            int row = row0 + mb * 16 + l15;
            if (row < N) {
#pragma unroll
                for (int nb = 0; nb < 2; ++nb)
                    hpre[mb][nb] = *(const uint2*)&hp[(size_t)row * 64 + wid * 16 + nb * 8 + q * 2];
#pragma unroll
                for (int kk = 0; kk < 4; ++kk)
                    bfr[kk][mb] = *(const bf16x8*)(obuf + (size_t)row * HD + kk * 32 + q * 8);
            } else {
#pragma unroll
                for (int nb = 0; nb < 2; ++nb) { hpre[mb][nb].x = 0u; hpre[mb][nb].y = 0u; }
#pragma unroll
                for (int kk = 0; kk < 4; ++kk) bfr[kk][mb] = (bf16x8)0;
            }
        }
        __syncthreads();

        // ---- GEMM1 ----
        f32x4 acc1[2][4];
#pragma unroll
        for (int mb = 0; mb < 2; ++mb)
#pragma unroll
            for (int nb = 0; nb < 4; ++nb) acc1[mb][nb] = (f32x4)0.f;
#pragma unroll
        for (int kk = 0; kk < 4; ++kk)
#pragma unroll
            for (int nb = 0; nb < 4; ++nb)
#pragma unroll
                for (int mb = 0; mb < 2; ++mb)
                    acc1[mb][nb] = __builtin_amdgcn_mfma_f32_16x16x32_bf16(w1f[kk][nb], bfr[kk][mb], acc1[mb][nb], 0, 0, 0);

        // ---- bias + LN partial ----
        f32x4 b1v[4];
#pragma unroll
        for (int nb = 0; nb < 4; ++nb) b1v[nb] = *(const f32x4*)&b1[wid * 64 + nb * 16 + q * 4];
#pragma unroll
        for (int mb = 0; mb < 2; ++mb) {
            float s = 0.f, ss = 0.f;
#pragma unroll
            for (int nb = 0; nb < 4; ++nb) {
#pragma unroll
                for (int rg = 0; rg < 4; ++rg) {
                    float v = acc1[mb][nb][rg] + b1v[nb][rg];
                    acc1[mb][nb][rg] = v;
                    s += v;
                    ss += v * v;
                }
            }
            s += __shfl_xor(s, 16, 64);
            s += __shfl_xor(s, 32, 64);
            ss += __shfl_xor(ss, 16, 64);
            ss += __shfl_xor(ss, 32, 64);
            if (q == 0) {
                s_part[(mb * 16 + l15) * 8 + wid * 2] = s;
                s_part[(mb * 16 + l15) * 8 + wid * 2 + 1] = ss;
            }
        }
        __syncthreads();

        // ---- finish LN + ReLU -> s_hm ----
        f32x4 g1v[4], bbv[4];
#pragma unroll
        for (int nb = 0; nb < 4; ++nb) {
            g1v[nb] = *(const f32x4*)&g1[wid * 64 + nb * 16 + q * 4];
            bbv[nb] = *(const f32x4*)&bb1[wid * 64 + nb * 16 + q * 4];
        }
#pragma unroll
        for (int mb = 0; mb < 2; ++mb) {
            int rl = mb * 16 + l15;
            f32x4 p0 = *(const f32x4*)&s_part[rl * 8];
            f32x4 p1 = *(const f32x4*)&s_part[rl * 8 + 4];
            float S = p0.x + p0.z + p1.x + p1.z;
            float SS = p0.y + p0.w + p1.y + p1.w;
            float mu = S * (1.f / 256.f);
            float var = SS * (1.f / 256.f) - mu * mu;
            float rstd = rsqrtf(var + LN_EPS);
#pragma unroll
            for (int nb = 0; nb < 4; ++nb) {
                u16x4 pk;
#pragma unroll
                for (int rg = 0; rg < 4; ++rg) {
                    float v = fmaxf((acc1[mb][nb][rg] - mu) * rstd * g1v[nb][rg] + bbv[nb][rg], 0.f);
                    pk[rg] = f2bf(v);
                }
                *(u16x4*)&s_hm[rl * HP2 + wid * 64 + nb * 16 + q * 4] = pk;
            }
        }
        __syncthreads();

        // ---- GEMM2 ----
        f32x4 acc2[2][2];
#pragma unroll
        for (int mb = 0; mb < 2; ++mb)
#pragma unroll
            for (int nb = 0; nb < 2; ++nb) acc2[mb][nb] = (f32x4)0.f;
#pragma unroll
        for (int kk = 0; kk < 8; ++kk) {
            bf16x8 hfr[2];
#pragma unroll
            for (int mb = 0; mb < 2; ++mb)
                hfr[mb] = *(const bf16x8*)&s_hm[(mb * 16 + l15) * HP2 + kk * 32 + q * 8];
#pragma unroll
            for (int nb = 0; nb < 2; ++nb)
#pragma unroll
                for (int mb = 0; mb < 2; ++mb)
                    acc2[mb][nb] = __builtin_amdgcn_mfma_f32_16x16x32_bf16(w2f[kk][nb], hfr[mb], acc2[mb][nb], 0, 0, 0);
        }

        // ---- epilogue: hp = bf16(h + out + b2) ; LN2 partials ----
        f32x4 b2v[2];
#pragma unroll
        for (int nb = 0; nb < 2; ++nb) b2v[nb] = *(const f32x4*)&b2[wid * 32 + nb * 16 + q * 4];

#pragma unroll
        for (int mb = 0; mb < 2; ++mb) {
            int row = row0 + mb * 16 + l15;
            float s2 = 0.f, ss2 = 0.f;
            if (row < N) {
#pragma unroll
                for (int nb = 0; nb < 2; ++nb) {
                    uint2 hv = hpre[mb][nb];
                    float h0 = u2f(hv.x << 16), h1 = u2f(hv.x & 0xffff0000u);
                    float h2 = u2f(hv.y << 16), h3 = u2f(hv.y & 0xffff0000u);
                    f32x4 v;
                    v[0] = h0 + acc2[mb][nb][0] + b2v[nb][0];
                    v[1] = h1 + acc2[mb][nb][1] + b2v[nb][1];
                    v[2] = h2 + acc2[mb][nb][2] + b2v[nb][2];
                    v[3] = h3 + acc2[mb][nb][3] + b2v[nb][3];
                    s2 += v[0] + v[1] + v[2] + v[3];
                    ss2 += v[0] * v[0] + v[1] * v[1] + v[2] * v[2] + v[3] * v[3];
                    uint2 pk;
                    pk.x = packbf(v[0], v[1]);
                    pk.y = packbf(v[2], v[3]);
                    *(uint2*)&hp[(size_t)row * 64 + wid * 16 + nb * 8 + q * 2] = pk;
                    acc2[mb][nb] = v;  // keep for fused LN
                }
            }
            if (fuse) {
                s2 += __shfl_xor(s2, 16, 64);
                s2 += __shfl_xor(s2, 32, 64);
                ss2 += __shfl_xor(ss2, 16, 64);
                ss2 += __shfl_xor(ss2, 32, 64);
                if (q == 0) {
                    s_part[(mb * 16 + l15) * 8 + wid * 2] = s2;
                    s_part[(mb * 16 + l15) * 8 + wid * 2 + 1] = ss2;
                }
            }
        }

        if (fuse) {
            __syncthreads();
            f32x4 gnv[2], bnv[2];
#pragma unroll
            for (int nb = 0; nb < 2; ++nb) {
                gnv[nb] = *(const f32x4*)&gnext[wid * 32 + nb * 16 + q * 4];
                bnv[nb] = *(const f32x4*)&btnext[wid * 32 + nb * 16 + q * 4];
            }
#pragma unroll
            for (int mb = 0; mb < 2; ++mb) {
                int rl = mb * 16 + l15;
                int row = row0 + rl;
                f32x4 p0 = *(const f32x4*)&s_part[rl * 8];
                f32x4 p1 = *(const f32x4*)&s_part[rl * 8 + 4];
                float S = p0.x + p0.z + p1.x + p1.z;
                float SS = p0.y + p0.w + p1.y + p1.w;
                float mu = S * (1.f / 128.f);
                float var = SS * (1.f / 128.f) - mu * mu;
                float rstd = rsqrtf(var + LN_EPS);
                if (row < N) {
#pragma unroll
                    for (int nb = 0; nb < 2; ++nb) {
                        float z0 = fmaxf((acc2[mb][nb][0] - mu) * rstd * gnv[nb][0] + bnv[nb][0], 0.f);
                        float z1 = fmaxf((acc2[mb][nb][1] - mu) * rstd * gnv[nb][1] + bnv[nb][1], 0.f);
                        float z2 = fmaxf((acc2[mb][nb][2] - mu) * rstd * gnv[nb][2] + bnv[nb][2], 0.f);
                        float z3 = fmaxf((acc2[mb][nb][3] - mu) * rstd * gnv[nb][3] + bnv[nb][3], 0.f);
                        uint2 pk;
                        pk.x = packbf(z0, z1);
                        pk.y = packbf(z2, z3);
                        *(uint2*)&zp[(size_t)row * 64 + wid * 16 + nb * 8 + q * 2] = pk;
                    }
                }
            }
        }
    }
}

// ---------------- pooling (sorted batch, packed bf16 h) ----------------
__global__ __launch_bounds__(256) void pool_kernel(const unsigned* __restrict__ hp,
                                                   const int* __restrict__ batch, int N,
                                                   float* __restrict__ pooled) {
    __shared__ int sb[2];
    __shared__ float red0[256], red1[256];
    int g = blockIdx.x;
    if (threadIdx.x == 0) {
        int lo = 0, hi = N;
        while (lo < hi) { int mid = (lo + hi) >> 1; if (batch[mid] < g) lo = mid + 1; else hi = mid; }
        sb[0] = lo;
        lo = 0; hi = N;
        int gq = g + 1;
        while (lo < hi) { int mid = (lo + hi) >> 1; if (batch[mid] < gq) lo = mid + 1; else hi = mid; }
        sb[1] = lo;
    }
    __syncthreads();
    int beg = sb[0], end = sb[1];
    int c = threadIdx.x & 63, str = threadIdx.x >> 6;
    float a0 = 0.f, a1 = 0.f;
    for (int r = beg + str; r < end; r += 4) {
        unsigned p = hp[(size_t)r * 64 + c];
        a0 += u2f(p << 16);
        a1 += u2f(p & 0xffff0000u);
    }
    red0[threadIdx.x] = a0;
    red1[threadIdx.x] = a1;
    __syncthreads();
    if (str == 0) {
        float s0 = red0[c] + red0[64 + c] + red0[128 + c] + red0[192 + c];
        float s1 = red1[c] + red1[64 + c] + red1[128 + c] + red1[192 + c];
        pooled[(size_t)g * HD + 2 * c] = s0;
        pooled[(size_t)g * HD + 2 * c + 1] = s1;
    }
}

// ---------------- classifier ----------------
__global__ __launch_bounds__(256) void cls_kernel(const float* __restrict__ pooled,
                                                  const float* __restrict__ W,
                                                  const float* __restrict__ b,
                                                  float* __restrict__ out, int G) {
    int gid = blockIdx.x * 256 + threadIdx.x;
    if (gid >= G * 2) return;
    int g = gid >> 1, cl = gid & 1;
    float acc = b[cl];
#pragma unroll 8
    for (int k = 0; k < HD; ++k) acc += pooled[g * HD + k] * W[k * 2 + cl];
    out[gid] = acc;
}

extern "C" void kernel_launch(void* const* d_in, const int* in_sizes, int n_in,
                              void* d_out, int out_size, void* d_ws, size_t ws_size,
                              hipStream_t stream) {
    const float* x     = (const float*)d_in[0];
    const int*   eidx  = (const int*)d_in[1];
    const int*   batch = (const int*)d_in[2];
    const float* enc_W = (const float*)d_in[3];
    const float* enc_b = (const float*)d_in[4];
    const float* t_all = (const float*)d_in[5];
    const float* W1    = (const float*)d_in[6];
    const float* b1    = (const float*)d_in[7];
    const float* g1    = (const float*)d_in[8];
    const float* bb1   = (const float*)d_in[9];
    const float* W2    = (const float*)d_in[10];
    const float* b2    = (const float*)d_in[11];
    const float* ln_g  = (const float*)d_in[12];
    const float* ln_b  = (const float*)d_in[13];
    const float* cls_W = (const float*)d_in[14];
    const float* cls_b = (const float*)d_in[15];
    float* out = (float*)d_out;

    const int N = in_sizes[0] / 7;
    const int E = in_sizes[1] / 2;
    const int L = in_sizes[5];
    const int G = out_size / 2;
    const int* src = eidx;
    const int* dst = eidx + E;

    char* p = (char*)d_ws;
    auto alloc = [&](size_t bytes) {
        char* q = p;
        p += (bytes + 255) & ~(size_t)255;
        return q;
    };
    unsigned* hp     = (unsigned*)alloc((size_t)N * 64 * 4);
    unsigned* zp     = (unsigned*)alloc((size_t)N * 64 * 4);
    unsigned* obuf   = (unsigned*)alloc((size_t)N * 64 * 4);
    float*    pooled = (float*)alloc((size_t)G * HD * 4);
    int* cnt      = (int*)alloc((size_t)N * 4);
    int* row_ptr  = (int*)alloc((size_t)(N + 1) * 4);
    int* cursor   = (int*)alloc((size_t)N * 4);
    int* blk_sums = (int*)alloc(256 * 4);
    int* esrc     = (int*)alloc((size_t)E * 4);
    ushort* W1t   = (ushort*)alloc((size_t)L * HD * HIDD * 2);
    ushort* W2t   = (ushort*)alloc((size_t)L * HD * HIDD * 2);

    const int nblkN = (N + 255) / 256;
    const int nblkE = (E + 255) / 256;
    const int ntiles = (N + 31) / 32;

    // fused encoder + layer-0 LN/ReLU, weight conversion
    enc_ln_kernel<<<(N + 3) / 4, 256, 0, stream>>>(x, enc_W, enc_b, ln_g, ln_b, hp, zp, N);
    {
        int tot2 = 2 * L * HD * HIDD;
        wconv_kernel<<<(tot2 + 255) / 256, 256, 0, stream>>>(W1, W2, W1t, W2t, L);
    }

    // CSR build
    hipMemsetAsync(cnt, 0, (size_t)N * 4, stream);
    count_kernel<<<nblkE, 256, 0, stream>>>(dst, cnt, E);
    scanA_kernel<<<nblkN, 256, 0, stream>>>(cnt, row_ptr, blk_sums, N);
    scanB_kernel<<<1, 256, 0, stream>>>(blk_sums, nblkN);
    scanC_kernel<<<nblkN, 256, 0, stream>>>(row_ptr, blk_sums, cursor, N);
    scatter_kernel<<<nblkE, 256, 0, stream>>>(src, dst, cursor, esrc, E);

    // layers
    for (int i = 0; i < L; ++i) {
        agg_kernel<<<(N + 11) / 12, 256, 0, stream>>>(zp, row_ptr, esrc, t_all, i, obuf, N);
        int fuse = (i + 1 < L) ? 1 : 0;
        const float* gn = ln_g + (size_t)(fuse ? i + 1 : i) * HD;
        const float* bn = ln_b + (size_t)(fuse ? i + 1 : i) * HD;
        mlp_kernel<<<512, 256, 0, stream>>>((const ushort*)obuf, hp,
                                            W1t + (size_t)i * HD * HIDD, b1 + (size_t)i * HIDD,
                                            g1 + (size_t)i * HIDD, bb1 + (size_t)i * HIDD,
                                            W2t + (size_t)i * HD * HIDD, b2 + (size_t)i * HD,
                                            gn, bn, zp, fuse, ntiles, N);
    }

    // pooling + classifier
    pool_kernel<<<G, 256, 0, stream>>>(hp, batch, N, pooled);
    cls_kernel<<<(G * 2 + 255) / 256, 256, 0, stream>>>(pooled, cls_W, cls_b, out, G);
}

// Round 15
// 443.967 us; speedup vs baseline: 1.0161x; 1.0161x over previous
//
#include <hip/hip_runtime.h>
#include <hip/hip_bf16.h>

#define HD 128
#define HIDD 256
#define EPS_MSG 1e-7f
#define EPS_SM 1e-16f
#define LN_EPS 1e-5f
#define HP2 264     // s_hm row stride (bf16 elems)
#define LOG2E 1.44269504f

typedef __attribute__((ext_vector_type(8))) short bf16x8;
typedef __attribute__((ext_vector_type(4))) float f32x4;
typedef __attribute__((ext_vector_type(4))) ushort u16x4;

static __device__ __forceinline__ float wave_reduce_sum(float v) {
#pragma unroll
    for (int off = 32; off >= 1; off >>= 1) v += __shfl_xor(v, off, 64);
    return v;
}

static __device__ __forceinline__ float u2f(unsigned v) {
    union { float f; unsigned u; } x;
    x.u = v;
    return x.f;
}
static __device__ __forceinline__ ushort f2bf(float f) {
    __hip_bfloat16 b = __float2bfloat16(f);
    return *(ushort*)&b;
}
static __device__ __forceinline__ unsigned packbf(float lo, float hi) {
    return (unsigned)f2bf(lo) | ((unsigned)f2bf(hi) << 16);
}

// ---------------- fused encoder + layer-0 LN+ReLU ----------------
__global__ __launch_bounds__(256) void enc_ln_kernel(const float* __restrict__ x,
                                                     const float* __restrict__ W,
                                                     const float* __restrict__ b,
                                                     const float* __restrict__ g,
                                                     const float* __restrict__ bt,
                                                     unsigned* __restrict__ hp,
                                                     unsigned* __restrict__ zp, int N) {
    int node = blockIdx.x * 4 + (threadIdx.x >> 6);
    int lane = threadIdx.x & 63;
    if (node >= N) return;
    float xr[7];
#pragma unroll
    for (int j = 0; j < 7; ++j) xr[j] = x[node * 7 + j];
    float v0 = b[lane], v1 = b[lane + 64];
#pragma unroll
    for (int j = 0; j < 7; ++j) {
        v0 = fmaf(xr[j], W[j * HD + lane], v0);
        v1 = fmaf(xr[j], W[j * HD + lane + 64], v1);
    }
    float s = wave_reduce_sum(v0 + v1);
    float ss = wave_reduce_sum(v0 * v0 + v1 * v1);
    float mu = s * (1.f / 128.f);
    float var = ss * (1.f / 128.f) - mu * mu;
    float rstd = rsqrtf(var + LN_EPS);
    float z0 = fmaxf((v0 - mu) * rstd * g[lane] + bt[lane], 0.f);
    float z1 = fmaxf((v1 - mu) * rstd * g[lane + 64] + bt[lane + 64], 0.f);
    int i0 = (2 * lane) & 63, i1 = (2 * lane + 1) & 63;
    float he_lo = __shfl(v0, i0), ho_lo = __shfl(v0, i1);
    float he_hi = __shfl(v1, i0), ho_hi = __shfl(v1, i1);
    float hce = (lane < 32) ? he_lo : he_hi;
    float hco = (lane < 32) ? ho_lo : ho_hi;
    hp[(size_t)node * 64 + lane] = packbf(hce, hco);
    float e_lo = __shfl(z0, i0), o_lo = __shfl(z0, i1);
    float e_hi = __shfl(z1, i0), o_hi = __shfl(z1, i1);
    float ce = (lane < 32) ? e_lo : e_hi;
    float co = (lane < 32) ? o_lo : o_hi;
    zp[(size_t)node * 64 + lane] = packbf(ce, co);
}

// ---------------- weight convert + transpose to bf16 ----------------
__global__ __launch_bounds__(256) void wconv_kernel(const float* __restrict__ W1,
                                                    const float* __restrict__ W2,
                                                    ushort* __restrict__ W1t,
                                                    ushort* __restrict__ W2t, int L) {
    int gid = blockIdx.x * 256 + threadIdx.x;
    int per = HD * HIDD;  // 32768
    int tot = L * per;
    if (gid < tot) {
        int l = gid / per, r = gid % per;
        int n = r >> 7, k = r & 127;
        W1t[gid] = f2bf(W1[(size_t)l * per + (size_t)k * HIDD + n]);
    } else if (gid < 2 * tot) {
        int g2 = gid - tot;
        int l = g2 / per, r = g2 % per;
        int n = r >> 8, k = r & 255;
        W2t[g2] = f2bf(W2[(size_t)l * per + (size_t)k * HD + n]);
    }
}

// ---------------- CSR build ----------------
__global__ __launch_bounds__(256) void count_kernel(const int* __restrict__ dst, int* __restrict__ cnt, int E) {
    int e = blockIdx.x * 256 + threadIdx.x;
    if (e < E) atomicAdd(&cnt[dst[e]], 1);
}

__global__ __launch_bounds__(256) void scanA_kernel(const int* __restrict__ cnt, int* __restrict__ row_ptr,
                                                    int* __restrict__ blk_sums, int n) {
    __shared__ int sb[256];
    int tid = threadIdx.x;
    int idx = blockIdx.x * 256 + tid;
    int v = (idx < n) ? cnt[idx] : 0;
    sb[tid] = v;
    __syncthreads();
#pragma unroll
    for (int off = 1; off < 256; off <<= 1) {
        int x = (tid >= off) ? sb[tid - off] : 0;
        __syncthreads();
        sb[tid] += x;
        __syncthreads();
    }
    if (idx < n) row_ptr[idx + 1] = sb[tid];
    if (tid == 255) blk_sums[blockIdx.x] = sb[255];
}

__global__ __launch_bounds__(256) void scanB_kernel(int* __restrict__ blk_sums, int nblk) {
    __shared__ int sb[256];
    int tid = threadIdx.x;
    int v = (tid < nblk) ? blk_sums[tid] : 0;
    sb[tid] = v;
    __syncthreads();
#pragma unroll
    for (int off = 1; off < 256; off <<= 1) {
        int x = (tid >= off) ? sb[tid - off] : 0;
        __syncthreads();
        sb[tid] += x;
        __syncthreads();
    }
    if (tid < nblk) blk_sums[tid] = sb[tid];
}

__global__ __launch_bounds__(256) void scanC_kernel(int* __restrict__ row_ptr, const int* __restrict__ blk_sums,
                                                    int* __restrict__ cursor, int n) {
    int idx = blockIdx.x * 256 + threadIdx.x;
    if (idx == 0) { row_ptr[0] = 0; cursor[0] = 0; }
    if (idx < n) {
        int b = idx >> 8;
        int v = row_ptr[idx + 1] + ((b > 0) ? blk_sums[b - 1] : 0);
        row_ptr[idx + 1] = v;
        if (idx + 1 < n) cursor[idx + 1] = v;
    }
}

__global__ __launch_bounds__(256) void scatter_kernel(const int* __restrict__ src, const int* __restrict__ dst,
                                                      int* __restrict__ cursor, int* __restrict__ esrc, int E) {
    int e = blockIdx.x * 256 + threadIdx.x;
    if (e < E) {
        int v = dst[e];
        int pos = atomicAdd(&cursor[v], 1);
        esrc[pos] = src[e];
    }
}

// ---------------- aggregation: dual-node per wave, 8 gathers in flight ----------------
__global__ __launch_bounds__(256) void agg_kernel(const unsigned* __restrict__ zp,
                                                  const int* __restrict__ row_ptr,
                                                  const int* __restrict__ esrc,
                                                  const float* __restrict__ t_all, int layer,
                                                  unsigned* __restrict__ obuf, int N) {
    int wid = threadIdx.x >> 6;
    int lane = threadIdx.x & 63;
    int nodeA = __builtin_amdgcn_readfirstlane(blockIdx.x * 8 + wid * 2);
    if (nodeA >= N) return;
    int nodeB = nodeA + 1;
    bool hasB = nodeB < N;

    const float tv = t_all[layer];
    const float M = 12.f * fmaxf(tv, 1.f);
    const float tv2 = tv * LOG2E;
    const float mM2 = -M * LOG2E;

    int begA = row_ptr[nodeA], endA = row_ptr[nodeA + 1];
    int begB = hasB ? row_ptr[nodeB] : 0;
    int endB = hasB ? row_ptr[nodeB + 1] : 0;

    unsigned psA = zp[(size_t)nodeA * 64 + lane];
    unsigned psB = hasB ? zp[(size_t)nodeB * 64 + lane] : 0u;

    float seA0 = 0.f, seA1 = 0.f, swA0 = 0.f, swA1 = 0.f;
    float teA0 = 0.f, teA1 = 0.f, twA0 = 0.f, twA1 = 0.f;
    float seB0 = 0.f, seB1 = 0.f, swB0 = 0.f, swB1 = 0.f;
    float teB0 = 0.f, teB1 = 0.f, twB0 = 0.f, twB1 = 0.f;

#define AGG_EDGE(P, E0, E1, W0, W1)                                   \
    {                                                                  \
        float a0 = u2f((P) << 16) + EPS_MSG;                           \
        float a1 = u2f((P) & 0xffff0000u) + EPS_MSG;                   \
        float x0 = __builtin_amdgcn_exp2f(fmaf(a0, tv2, mM2));         \
        float x1 = __builtin_amdgcn_exp2f(fmaf(a1, tv2, mM2));         \
        E0 += x0;                                                      \
        E1 += x1;                                                      \
        W0 = fmaf(x0, a0, W0);                                         \
        W1 = fmaf(x1, a1, W1);                                         \
    }

    int eA = begA, eB = begB;

    // ---- main: 4 edges from A + 4 edges from B per iteration (8 gathers in flight) ----
    while (eA + 4 <= endA && eB + 4 <= endB) {
        int a0i = esrc[eA], a1i = esrc[eA + 1], a2i = esrc[eA + 2], a3i = esrc[eA + 3];
        int b0i = esrc[eB], b1i = esrc[eB + 1], b2i = esrc[eB + 2], b3i = esrc[eB + 3];
        unsigned pA0 = zp[(size_t)a0i * 64 + lane];
        unsigned pA1 = zp[(size_t)a1i * 64 + lane];
        unsigned pA2 = zp[(size_t)a2i * 64 + lane];
        unsigned pA3 = zp[(size_t)a3i * 64 + lane];
        unsigned pB0 = zp[(size_t)b0i * 64 + lane];
        unsigned pB1 = zp[(size_t)b1i * 64 + lane];
        unsigned pB2 = zp[(size_t)b2i * 64 + lane];
        unsigned pB3 = zp[(size_t)b3i * 64 + lane];
        AGG_EDGE(pA0, seA0, seA1, swA0, swA1)
        AGG_EDGE(pA1, seA0, seA1, swA0, swA1)
        AGG_EDGE(pA2, teA0, teA1, twA0, twA1)
        AGG_EDGE(pA3, teA0, teA1, twA0, twA1)
        AGG_EDGE(pB0, seB0, seB1, swB0, swB1)
        AGG_EDGE(pB1, seB0, seB1, swB0, swB1)
        AGG_EDGE(pB2, teB0, teB1, twB0, twB1)
        AGG_EDGE(pB3, teB0, teB1, twB0, twB1)
        eA += 4;
        eB += 4;
    }
    // ---- tail A: 4-deep then scalar ----
    while (eA + 4 <= endA) {
        int a0i = esrc[eA], a1i = esrc[eA + 1], a2i = esrc[eA + 2], a3i = esrc[eA + 3];
        unsigned pA0 = zp[(size_t)a0i * 64 + lane];
        unsigned pA1 = zp[(size_t)a1i * 64 + lane];
        unsigned pA2 = zp[(size_t)a2i * 64 + lane];
        unsigned pA3 = zp[(size_t)a3i * 64 + lane];
        AGG_EDGE(pA0, seA0, seA1, swA0, swA1)
        AGG_EDGE(pA1, seA0, seA1, swA0, swA1)
        AGG_EDGE(pA2, teA0, teA1, twA0, twA1)
        AGG_EDGE(pA3, teA0, teA1, twA0, twA1)
        eA += 4;
    }
    for (; eA < endA; ++eA) {
        unsigned p0 = zp[(size_t)esrc[eA] * 64 + lane];
        AGG_EDGE(p0, seA0, seA1, swA0, swA1)
    }
    // ---- tail B: 4-deep then scalar ----
    while (eB + 4 <= endB) {
        int b0i = esrc[eB], b1i = esrc[eB + 1], b2i = esrc[eB + 2], b3i = esrc[eB + 3];
        unsigned pB0 = zp[(size_t)b0i * 64 + lane];
        unsigned pB1 = zp[(size_t)b1i * 64 + lane];
        unsigned pB2 = zp[(size_t)b2i * 64 + lane];
        unsigned pB3 = zp[(size_t)b3i * 64 + lane];
        AGG_EDGE(pB0, seB0, seB1, swB0, swB1)
        AGG_EDGE(pB1, seB0, seB1, swB0, swB1)
        AGG_EDGE(pB2, teB0, teB1, twB0, twB1)
        AGG_EDGE(pB3, teB0, teB1, twB0, twB1)
        eB += 4;
    }
    for (; eB < endB; ++eB) {
        unsigned p0 = zp[(size_t)esrc[eB] * 64 + lane];
        AGG_EDGE(p0, seB0, seB1, swB0, swB1)
    }
#undef AGG_EDGE

    // ---- finalize node A ----
    {
        float se0 = seA0 + teA0, se1 = seA1 + teA1;
        float sw0 = swA0 + twA0, sw1 = swA1 + twA1;
        float a0 = (endA > begA) ? sw0 / (se0 + EPS_SM) : 0.f;
        float a1 = (endA > begA) ? sw1 / (se1 + EPS_SM) : 0.f;
        float z0 = u2f(psA << 16), z1 = u2f(psA & 0xffff0000u);
        obuf[(size_t)nodeA * 64 + lane] = packbf(a0 + z0, a1 + z1);
    }
    // ---- finalize node B ----
    if (hasB) {
        float se0 = seB0 + teB0, se1 = seB1 + teB1;
        float sw0 = swB0 + twB0, sw1 = swB1 + twB1;
        float a0 = (endB > begB) ? sw0 / (se0 + EPS_SM) : 0.f;
        float a1 = (endB > begB) ? sw1 / (se1 + EPS_SM) : 0.f;
        float z0 = u2f(psB << 16), z1 = u2f(psB & 0xffff0000u);
        obuf[(size_t)nodeB * 64 + lane] = packbf(a0 + z0, a1 + z1);
    }
}

// ---------------- persistent MFMA MLP (R8 structure): hp += relu(LN(obuf@W1+b1))@W2 + b2 ----------------
__global__ __launch_bounds__(256) void mlp_kernel(const ushort* __restrict__ obuf,
                                                  unsigned* __restrict__ hp,
                                                  const ushort* __restrict__ W1t, const float* __restrict__ b1,
                                                  const float* __restrict__ g1, const float* __restrict__ bb1,
                                                  const ushort* __restrict__ W2t, const float* __restrict__ b2,
                                                  const float* __restrict__ gnext, const float* __restrict__ btnext,
                                                  unsigned* __restrict__ zp, int fuse,
                                                  int ntiles, int N) {
    __shared__ ushort s_hm[32 * HP2];   // 16896 B
    __shared__ float s_part[32 * 8];    // 1024 B

    int tid = threadIdx.x;
    int wid = tid >> 6, lane = tid & 63;
    int l15 = lane & 15, q = lane >> 4;

    // ---- hoist ALL weight fragments (tile-invariant) ----
    bf16x8 w1f[4][4];
#pragma unroll
    for (int kk = 0; kk < 4; ++kk)
#pragma unroll
        for (int nb = 0; nb < 4; ++nb)
            w1f[kk][nb] = *(const bf16x8*)&W1t[(size_t)(wid * 64 + nb * 16 + l15) * HD + kk * 32 + q * 8];
    bf16x8 w2f[8][2];
#pragma unroll
    for (int kk = 0; kk < 8; ++kk)
#pragma unroll
        for (int nb = 0; nb < 2; ++nb)
            w2f[kk][nb] = *(const bf16x8*)&W2t[(size_t)(wid * 32 + nb * 16 + l15) * HIDD + kk * 32 + q * 8];

    for (int tile = blockIdx.x; tile < ntiles; tile += gridDim.x) {
        int row0 = tile * 32;

        // ---- per-tile input loads ----
        uint2 hpre[2][2];
        bf16x8 bfr[4][2];
#pragma unroll
        for (int mb = 0; mb < 2; ++mb) {
            int row = row0 + mb * 16 + l15;
            if (row < N) {
#pragma unroll
                for (int nb = 0; nb < 2; ++nb)
                    hpre[mb][nb] = *(const uint2*)&hp[(size_t)row * 64 + wid * 16 + nb * 8 + q * 2];
#pragma unroll
                for (int kk = 0; kk < 4; ++kk)
                    bfr[kk][mb] = *(const bf16x8*)(obuf + (size_t)row * HD + kk * 32 + q * 8);
            } else {
#pragma unroll
                for (int nb = 0; nb < 2; ++nb) { hpre[mb][nb].x = 0u; hpre[mb][nb].y = 0u; }
#pragma unroll
                for (int kk = 0; kk < 4; ++kk) bfr[kk][mb] = (bf16x8)0;
            }
        }
        __syncthreads();

        // ---- GEMM1 ----
        f32x4 acc1[2][4];
#pragma unroll
        for (int mb = 0; mb < 2; ++mb)
#pragma unroll
            for (int nb = 0; nb < 4; ++nb) acc1[mb][nb] = (f32x4)0.f;
#pragma unroll
        for (int kk = 0; kk < 4; ++kk)
#pragma unroll
            for (int nb = 0; nb < 4; ++nb)
#pragma unroll
                for (int mb = 0; mb < 2; ++mb)
                    acc1[mb][nb] = __builtin_amdgcn_mfma_f32_16x16x32_bf16(w1f[kk][nb], bfr[kk][mb], acc1[mb][nb], 0, 0, 0);

        // ---- bias + LN partial ----
        f32x4 b1v[4];
#pragma unroll
        for (int nb = 0; nb < 4; ++nb) b1v[nb] = *(const f32x4*)&b1[wid * 64 + nb * 16 + q * 4];
#pragma unroll
        for (int mb = 0; mb < 2; ++mb) {
            float s = 0.f, ss = 0.f;
#pragma unroll
            for (int nb = 0; nb < 4; ++nb) {
#pragma unroll
                for (int rg = 0; rg < 4; ++rg) {
                    float v = acc1[mb][nb][rg] + b1v[nb][rg];
                    acc1[mb][nb][rg] = v;
                    s += v;
                    ss += v * v;
                }
            }
            s += __shfl_xor(s, 16, 64);
            s += __shfl_xor(s, 32, 64);
            ss += __shfl_xor(ss, 16, 64);
            ss += __shfl_xor(ss, 32, 64);
            if (q == 0) {
                s_part[(mb * 16 + l15) * 8 + wid * 2] = s;
                s_part[(mb * 16 + l15) * 8 + wid * 2 + 1] = ss;
            }
        }
        __syncthreads();

        // ---- finish LN + ReLU -> s_hm ----
        f32x4 g1v[4], bbv[4];
#pragma unroll
        for (int nb = 0; nb < 4; ++nb) {
            g1v[nb] = *(const f32x4*)&g1[wid * 64 + nb * 16 + q * 4];
            bbv[nb] = *(const f32x4*)&bb1[wid * 64 + nb * 16 + q * 4];
        }
#pragma unroll
        for (int mb = 0; mb < 2; ++mb) {
            int rl = mb * 16 + l15;
            f32x4 p0 = *(const f32x4*)&s_part[rl * 8];
            f32x4 p1 = *(const f32x4*)&s_part[rl * 8 + 4];
            float S = p0.x + p0.z + p1.x + p1.z;
            float SS = p0.y + p0.w + p1.y + p1.w;
            float mu = S * (1.f / 256.f);
            float var = SS * (1.f / 256.f) - mu * mu;
            float rstd = rsqrtf(var + LN_EPS);
#pragma unroll
            for (int nb = 0; nb < 4; ++nb) {
                u16x4 pk;
#pragma unroll
                for (int rg = 0; rg < 4; ++rg) {
                    float v = fmaxf((acc1[mb][nb][rg] - mu) * rstd * g1v[nb][rg] + bbv[nb][rg], 0.f);
                    pk[rg] = f2bf(v);
                }
                *(u16x4*)&s_hm[rl * HP2 + wid * 64 + nb * 16 + q * 4] = pk;
            }
        }
        __syncthreads();

        // ---- GEMM2 ----
        f32x4 acc2[2][2];
#pragma unroll
        for (int mb = 0; mb < 2; ++mb)
#pragma unroll
            for (int nb = 0; nb < 2; ++nb) acc2[mb][nb] = (f32x4)0.f;
#pragma unroll
        for (int kk = 0; kk < 8; ++kk) {
            bf16x8 hfr[2];
#pragma unroll
            for (int mb = 0; mb < 2; ++mb)
                hfr[mb] = *(const bf16x8*)&s_hm[(mb * 16 + l15) * HP2 + kk * 32 + q * 8];
#pragma unroll
            for (int nb = 0; nb < 2; ++nb)
#pragma unroll
                for (int mb = 0; mb < 2; ++mb)
                    acc2[mb][nb] = __builtin_amdgcn_mfma_f32_16x16x32_bf16(w2f[kk][nb], hfr[mb], acc2[mb][nb], 0, 0, 0);
        }

        // ---- epilogue: hp = bf16(h + out + b2) ; LN2 partials ----
        f32x4 b2v[2];
#pragma unroll
        for (int nb = 0; nb < 2; ++nb) b2v[nb] = *(const f32x4*)&b2[wid * 32 + nb * 16 + q * 4];

#pragma unroll
        for (int mb = 0; mb < 2; ++mb) {
            int row = row0 + mb * 16 + l15;
            float s2 = 0.f, ss2 = 0.f;
            if (row < N) {
#pragma unroll
                for (int nb = 0; nb < 2; ++nb) {
                    uint2 hv = hpre[mb][nb];
                    float h0 = u2f(hv.x << 16), h1 = u2f(hv.x & 0xffff0000u);
                    float h2 = u2f(hv.y << 16), h3 = u2f(hv.y & 0xffff0000u);
                    f32x4 v;
                    v[0] = h0 + acc2[mb][nb][0] + b2v[nb][0];
                    v[1] = h1 + acc2[mb][nb][1] + b2v[nb][1];
                    v[2] = h2 + acc2[mb][nb][2] + b2v[nb][2];
                    v[3] = h3 + acc2[mb][nb][3] + b2v[nb][3];
                    s2 += v[0] + v[1] + v[2] + v[3];
                    ss2 += v[0] * v[0] + v[1] * v[1] + v[2] * v[2] + v[3] * v[3];
                    uint2 pk;
                    pk.x = packbf(v[0], v[1]);
                    pk.y = packbf(v[2], v[3]);
                    *(uint2*)&hp[(size_t)row * 64 + wid * 16 + nb * 8 + q * 2] = pk;
                    acc2[mb][nb] = v;  // keep for fused LN
                }
            }
            if (fuse) {
                s2 += __shfl_xor(s2, 16, 64);
                s2 += __shfl_xor(s2, 32, 64);
                ss2 += __shfl_xor(ss2, 16, 64);
                ss2 += __shfl_xor(ss2, 32, 64);
                if (q == 0) {
                    s_part[(mb * 16 + l15) * 8 + wid * 2] = s2;
                    s_part[(mb * 16 + l15) * 8 + wid * 2 + 1] = ss2;
                }
            }
        }

        if (fuse) {
            __syncthreads();
            f32x4 gnv[2], bnv[2];
#pragma unroll
            for (int nb = 0; nb < 2; ++nb) {
                gnv[nb] = *(const f32x4*)&gnext[wid * 32 + nb * 16 + q * 4];
                bnv[nb] = *(const f32x4*)&btnext[wid * 32 + nb * 16 + q * 4];
            }
#pragma unroll
            for (int mb = 0; mb < 2; ++mb) {
                int rl = mb * 16 + l15;
                int row = row0 + rl;
                f32x4 p0 = *(const f32x4*)&s_part[rl * 8];
                f32x4 p1 = *(const f32x4*)&s_part[rl * 8 + 4];
                float S = p0.x + p0.z + p1.x + p1.z;
                float SS = p0.y + p0.w + p1.y + p1.w;
                float mu = S * (1.f / 128.f);
                float var = SS * (1.f / 128.f) - mu * mu;
                float rstd = rsqrtf(var + LN_EPS);
                if (row < N) {
#pragma unroll
                    for (int nb = 0; nb < 2; ++nb) {
                        float z0 = fmaxf((acc2[mb][nb][0] - mu) * rstd * gnv[nb][0] + bnv[nb][0], 0.f);
                        float z1 = fmaxf((acc2[mb][nb][1] - mu) * rstd * gnv[nb][1] + bnv[nb][1], 0.f);
                        float z2 = fmaxf((acc2[mb][nb][2] - mu) * rstd * gnv[nb][2] + bnv[nb][2], 0.f);
                        float z3 = fmaxf((acc2[mb][nb][3] - mu) * rstd * gnv[nb][3] + bnv[nb][3], 0.f);
                        uint2 pk;
                        pk.x = packbf(z0, z1);
                        pk.y = packbf(z2, z3);
                        *(uint2*)&zp[(size_t)row * 64 + wid * 16 + nb * 8 + q * 2] = pk;
                    }
                }
            }
        }
    }
}

// ---------------- pooling (sorted batch, packed bf16 h) ----------------
__global__ __launch_bounds__(256) void pool_kernel(const unsigned* __restrict__ hp,
                                                   const int* __restrict__ batch, int N,
                                                   float* __restrict__ pooled) {
    __shared__ int sb[2];
    __shared__ float red0[256], red1[256];
    int g = blockIdx.x;
    if (threadIdx.x == 0) {
        int lo = 0, hi = N;
        while (lo < hi) { int mid = (lo + hi) >> 1; if (batch[mid] < g) lo = mid + 1; else hi = mid; }
        sb[0] = lo;
        lo = 0; hi = N;
        int gq = g + 1;
        while (lo < hi) { int mid = (lo + hi) >> 1; if (batch[mid] < gq) lo = mid + 1; else hi = mid; }
        sb[1] = lo;
    }
    __syncthreads();
    int beg = sb[0], end = sb[1];
    int c = threadIdx.x & 63, str = threadIdx.x >> 6;
    float a0 = 0.f, a1 = 0.f;
    for (int r = beg + str; r < end; r += 4) {
        unsigned p = hp[(size_t)r * 64 + c];
        a0 += u2f(p << 16);
        a1 += u2f(p & 0xffff0000u);
    }
    red0[threadIdx.x] = a0;
    red1[threadIdx.x] = a1;
    __syncthreads();
    if (str == 0) {
        float s0 = red0[c] + red0[64 + c] + red0[128 + c] + red0[192 + c];
        float s1 = red1[c] + red1[64 + c] + red1[128 + c] + red1[192 + c];
        pooled[(size_t)g * HD + 2 * c] = s0;
        pooled[(size_t)g * HD + 2 * c + 1] = s1;
    }
}

// ---------------- classifier ----------------
__global__ __launch_bounds__(256) void cls_kernel(const float* __restrict__ pooled,
                                                  const float* __restrict__ W,
                                                  const float* __restrict__ b,
                                                  float* __restrict__ out, int G) {
    int gid = blockIdx.x * 256 + threadIdx.x;
    if (gid >= G * 2) return;
    int g = gid >> 1, cl = gid & 1;
    float acc = b[cl];
#pragma unroll 8
    for (int k = 0; k < HD; ++k) acc += pooled[g * HD + k] * W[k * 2 + cl];
    out[gid] = acc;
}

extern "C" void kernel_launch(void* const* d_in, const int* in_sizes, int n_in,
                              void* d_out, int out_size, void* d_ws, size_t ws_size,
                              hipStream_t stream) {
    const float* x     = (const float*)d_in[0];
    const int*   eidx  = (const int*)d_in[1];
    const int*   batch = (const int*)d_in[2];
    const float* enc_W = (const float*)d_in[3];
    const float* enc_b = (const float*)d_in[4];
    const float* t_all = (const float*)d_in[5];
    const float* W1    = (const float*)d_in[6];
    const float* b1    = (const float*)d_in[7];
    const float* g1    = (const float*)d_in[8];
    const float* bb1   = (const float*)d_in[9];
    const float* W2    = (const float*)d_in[10];
    const float* b2    = (const float*)d_in[11];
    const float* ln_g  = (const float*)d_in[12];
    const float* ln_b  = (const float*)d_in[13];
    const float* cls_W = (const float*)d_in[14];
    const float* cls_b = (const float*)d_in[15];
    float* out = (float*)d_out;

    const int N = in_sizes[0] / 7;
    const int E = in_sizes[1] / 2;
    const int L = in_sizes[5];
    const int G = out_size / 2;
    const int* src = eidx;
    const int* dst = eidx + E;

    char* p = (char*)d_ws;
    auto alloc = [&](size_t bytes) {
        char* q = p;
        p += (bytes + 255) & ~(size_t)255;
        return q;
    };
    unsigned* hp     = (unsigned*)alloc((size_t)N * 64 * 4);
    unsigned* zp     = (unsigned*)alloc((size_t)N * 64 * 4);
    unsigned* obuf   = (unsigned*)alloc((size_t)N * 64 * 4);
    float*    pooled = (float*)alloc((size_t)G * HD * 4);
    int* cnt      = (int*)alloc((size_t)N * 4);
    int* row_ptr  = (int*)alloc((size_t)(N + 1) * 4);
    int* cursor   = (int*)alloc((size_t)N * 4);
    int* blk_sums = (int*)alloc(256 * 4);
    int* esrc     = (int*)alloc((size_t)E * 4);
    ushort* W1t   = (ushort*)alloc((size_t)L * HD * HIDD * 2);
    ushort* W2t   = (ushort*)alloc((size_t)L * HD * HIDD * 2);

    const int nblkN = (N + 255) / 256;
    const int nblkE = (E + 255) / 256;
    const int ntiles = (N + 31) / 32;

    // fused encoder + layer-0 LN/ReLU, weight conversion
    enc_ln_kernel<<<(N + 3) / 4, 256, 0, stream>>>(x, enc_W, enc_b, ln_g, ln_b, hp, zp, N);
    {
        int tot2 = 2 * L * HD * HIDD;
        wconv_kernel<<<(tot2 + 255) / 256, 256, 0, stream>>>(W1, W2, W1t, W2t, L);
    }

    // CSR build
    hipMemsetAsync(cnt, 0, (size_t)N * 4, stream);
    count_kernel<<<nblkE, 256, 0, stream>>>(dst, cnt, E);
    scanA_kernel<<<nblkN, 256, 0, stream>>>(cnt, row_ptr, blk_sums, N);
    scanB_kernel<<<1, 256, 0, stream>>>(blk_sums, nblkN);
    scanC_kernel<<<nblkN, 256, 0, stream>>>(row_ptr, blk_sums, cursor, N);
    scatter_kernel<<<nblkE, 256, 0, stream>>>(src, dst, cursor, esrc, E);

    // layers
    for (int i = 0; i < L; ++i) {
        agg_kernel<<<(N + 7) / 8, 256, 0, stream>>>(zp, row_ptr, esrc, t_all, i, obuf, N);
        int fuse = (i + 1 < L) ? 1 : 0;
        const float* gn = ln_g + (size_t)(fuse ? i + 1 : i) * HD;
        const float* bn = ln_b + (size_t)(fuse ? i + 1 : i) * HD;
        mlp_kernel<<<512, 256, 0, stream>>>((const ushort*)obuf, hp,
                                            W1t + (size_t)i * HD * HIDD, b1 + (size_t)i * HIDD,
                                            g1 + (size_t)i * HIDD, bb1 + (size_t)i * HIDD,
                                            W2t + (size_t)i * HD * HIDD, b2 + (size_t)i * HD,
                                            gn, bn, zp, fuse, ntiles, N);
    }

    // pooling + classifier
    pool_kernel<<<G, 256, 0, stream>>>(hp, batch, N, pooled);
    cls_kernel<<<(G * 2 + 255) / 256, 256, 0, stream>>>(pooled, cls_W, cls_b, out, G);
}